// Round 3
// baseline (616.901 us; speedup 1.0000x reference)
//
#include <hip/hip_runtime.h>

#define NN 50000      // nodes
#define NR 10         // relations (one direction)
#define R2 21         // 2*NR+1
#define NE 500000     // triples
#define NB 16384      // batch
#define HID 64
#define SCAN_B 1024
#define M_CELLS (R2 * NN)   // 1,050,000 cells (ss-major: col = ss*NN + src)
#define COL_MASK 0x1FFFFF   // col fits in 21 bits (max 1,049,999)
#define GC_COLS 64

// ---- hist: celloff cell counts (dst*21+ss) w/ rank capture; batch flags ------
// 4 triples/thread via 3x int4 loads (stride 48 B, 16-aligned).
__global__ void hist_kernel(const int* __restrict__ triples, const int* __restrict__ batch,
                            int* __restrict__ celloff, int* __restrict__ rank,
                            int* __restrict__ flag) {
    int t = blockIdx.x * blockDim.x + threadIdx.x;
    if (t < NE / 4) {
        const int4* tp = (const int4*)(triples + 12 * (size_t)t);
        int4 a = tp[0], b = tp[1], c = tp[2];
        int s[4] = {a.x, a.w, b.z, c.y};
        int p[4] = {a.y, b.x, b.w, c.z};
        int o[4] = {a.z, b.y, c.x, c.w};
#pragma unroll
        for (int i = 0; i < 4; ++i) {
            int e = 4 * t + i;
            rank[e]      = atomicAdd(celloff + s[i] * R2 + p[i], 1);        // fwd
            rank[e + NE] = atomicAdd(celloff + o[i] * R2 + (p[i] + NR), 1); // bwd
        }
    } else if (t < NE / 4 + NN) {
        int v = t - NE / 4;
        celloff[v * R2 + 2 * NR] = 1;   // self-loop cell: always exactly 1
    } else if (t < NE / 4 + NN + 2 * NB) {
        int j = t - (NE / 4 + NN);
        int node = (j < NB) ? batch[3 * j] : batch[3 * (j - NB) + 2];
        flag[node] = 1;                 // idempotent
    }
}

// ---- 2-level exclusive scan, 2 items per thread ------------------------------
// scan1 optionally emits cnt8 (the col-count permutation) while it still has
// the raw counts in hand: cell i=(x*R2+j) -> cnt8[perm(j)*NN+x].
__global__ void scan1_kernel(int* __restrict__ data, int* __restrict__ bsums, int M,
                             unsigned char* __restrict__ cnt8) {
    __shared__ int sm[SCAN_B];
    int i0 = (blockIdx.x * SCAN_B + threadIdx.x) * 2;
    int x0 = (i0     < M) ? data[i0]     : 0;
    int x1 = (i0 + 1 < M) ? data[i0 + 1] : 0;
    if (cnt8) {
        if (i0 < M) {
            unsigned x = (unsigned)i0 / R2; int j = i0 - (int)x * R2;
            int slot = (j < NR ? j + NR : (j < 2 * NR ? j - NR : 2 * NR)) * NN + (int)x;
            cnt8[slot] = (unsigned char)min(x0, 255);
        }
        if (i0 + 1 < M) {
            unsigned x = (unsigned)(i0 + 1) / R2; int j = (i0 + 1) - (int)x * R2;
            int slot = (j < NR ? j + NR : (j < 2 * NR ? j - NR : 2 * NR)) * NN + (int)x;
            cnt8[slot] = (unsigned char)min(x1, 255);
        }
    }
    int s = x0 + x1;
    sm[threadIdx.x] = s; __syncthreads();
    for (int off = 1; off < SCAN_B; off <<= 1) {
        int v = (threadIdx.x >= off) ? sm[threadIdx.x - off] : 0;
        __syncthreads();
        sm[threadIdx.x] += v;
        __syncthreads();
    }
    int excl = sm[threadIdx.x] - s;
    if (i0     < M) data[i0]     = excl;
    if (i0 + 1 < M) data[i0 + 1] = excl + x0;
    if (threadIdx.x == SCAN_B - 1) bsums[blockIdx.x] = sm[SCAN_B - 1];
}
__global__ void scan2_kernel(int* __restrict__ bsums, int nb, int* __restrict__ total_out) {
    __shared__ int sm[SCAN_B];
    int x = (threadIdx.x < nb) ? bsums[threadIdx.x] : 0;
    sm[threadIdx.x] = x; __syncthreads();
    for (int off = 1; off < SCAN_B; off <<= 1) {
        int v = (threadIdx.x >= off) ? sm[threadIdx.x - off] : 0;
        __syncthreads();
        sm[threadIdx.x] += v;
        __syncthreads();
    }
    if (threadIdx.x < nb) bsums[threadIdx.x] = sm[threadIdx.x] - x;
    if (threadIdx.x == SCAN_B - 1) *total_out = sm[SCAN_B - 1];
}
__global__ void scan3_kernel(int* __restrict__ data, const int* __restrict__ bsums, int M) {
    int i0 = (blockIdx.x * SCAN_B + threadIdx.x) * 2;
    int b = bsums[blockIdx.x];
    if (i0     < M) data[i0]     += b;
    if (i0 + 1 < M) data[i0 + 1] += b;
}

// ---- scatter (atomic-free via rank) + mark needed cols -----------------------
// pay = col | (cnt<<21): count packed so layer1/2 never gather vals.
__global__ void scatter_kernel(const int* __restrict__ triples,
                               const int* __restrict__ celloff,
                               const int* __restrict__ rank,
                               const int* __restrict__ flag,
                               const unsigned char* __restrict__ cnt8,
                               int* __restrict__ pay,
                               int* __restrict__ colflag) {
    int t = blockIdx.x * blockDim.x + threadIdx.x;
    if (t < NE / 4) {
        const int4* tp = (const int4*)(triples + 12 * (size_t)t);
        int4 a = tp[0], b = tp[1], c = tp[2];
        int s[4] = {a.x, a.w, b.z, c.y};
        int p[4] = {a.y, b.x, b.w, c.z};
        int o[4] = {a.z, b.y, c.x, c.w};
        int4 rka = ((const int4*)rank)[t];
        int4 rkb = ((const int4*)(rank + NE))[t];
        int ra[4] = {rka.x, rka.y, rka.z, rka.w};
        int rb[4] = {rkb.x, rkb.y, rkb.z, rkb.w};
#pragma unroll
        for (int i = 0; i < 4; ++i) {
            int col1 = p[i] * NN + o[i];
            int pos1 = celloff[s[i] * R2 + p[i]] + ra[i];
            pay[pos1] = col1 | ((int)cnt8[col1] << 21);
            int col2 = (p[i] + NR) * NN + s[i];
            int pos2 = celloff[o[i] * R2 + (p[i] + NR)] + rb[i];
            pay[pos2] = col2 | ((int)cnt8[col2] << 21);
            if (flag[s[i]]) colflag[col1] = 1;
            if (flag[o[i]]) colflag[col2] = 1;
        }
    } else if (t < NE / 4 + NN) {
        int v = t - NE / 4;
        int pos = celloff[v * R2 + 2 * NR];
        int col = 2 * NR * NN + v;
        pay[pos] = col | (1 << 21);
        if (flag[v]) colflag[col] = 1;
    }
}

// ---- layer 1: wave per dst; packed-cnt LUT; ILP-8 groups, NO scalar tail -----
// Padding lanes carry colv=0 -> lut[0]=0, so partial groups contribute zero.
// Also folds collist emit (coloff -> collist) since layer1 runs after the scan.
__global__ __launch_bounds__(256) void layer1_kernel(const int* __restrict__ celloff,
                                                     const int* __restrict__ pay,
                                                     const float* __restrict__ w0,
                                                     const float* __restrict__ b0,
                                                     const int* __restrict__ coloff,
                                                     int* __restrict__ collist,
                                                     float* __restrict__ h) {
    __shared__ float lut[256];
    lut[threadIdx.x] = threadIdx.x ? 1.0f / (float)threadIdx.x : 0.f;   // lut[0]=0
    int t = blockIdx.x * blockDim.x + threadIdx.x;
    if (t < M_CELLS) {                        // collist fold (grid covers 3.2M threads)
        int a = coloff[t], b2 = coloff[t + 1];
        if (b2 > a) collist[a] = t;
    }
    __syncthreads();
    int wv = t >> 6;
    int lane = threadIdx.x & 63;
    if (wv >= NN) return;
    int dst = __builtin_amdgcn_readfirstlane(wv);
    int beg = celloff[dst * R2];
    int end = celloff[(dst + 1) * R2];
    float acc = b0[lane];
    for (int base = beg; base < end; base += 64) {
        int idx = base + lane;
        int colv = (idx < end) ? pay[idx] : 0;          // cnt=0 -> v=0
        int m = __builtin_amdgcn_readfirstlane(min(64, end - base));
        for (int e = 0; e < m; e += 8) {                // full-8 groups, zero-padded
            int c0p = __shfl(colv, e,     64);
            int c1p = __shfl(colv, e + 1, 64);
            int c2p = __shfl(colv, e + 2, 64);
            int c3p = __shfl(colv, e + 3, 64);
            int c4p = __shfl(colv, e + 4, 64);
            int c5p = __shfl(colv, e + 5, 64);
            int c6p = __shfl(colv, e + 6, 64);
            int c7p = __shfl(colv, e + 7, 64);
            float f0 = w0[(size_t)(c0p & COL_MASK) * HID + lane];
            float f1 = w0[(size_t)(c1p & COL_MASK) * HID + lane];
            float f2 = w0[(size_t)(c2p & COL_MASK) * HID + lane];
            float f3 = w0[(size_t)(c3p & COL_MASK) * HID + lane];
            float f4 = w0[(size_t)(c4p & COL_MASK) * HID + lane];
            float f5 = w0[(size_t)(c5p & COL_MASK) * HID + lane];
            float f6 = w0[(size_t)(c6p & COL_MASK) * HID + lane];
            float f7 = w0[(size_t)(c7p & COL_MASK) * HID + lane];
            acc += lut[(unsigned)c0p >> 21] * f0;
            acc += lut[(unsigned)c1p >> 21] * f1;
            acc += lut[(unsigned)c2p >> 21] * f2;
            acc += lut[(unsigned)c3p >> 21] * f3;
            acc += lut[(unsigned)c4p >> 21] * f4;
            acc += lut[(unsigned)c5p >> 21] * f5;
            acc += lut[(unsigned)c6p >> 21] * f6;
            acc += lut[(unsigned)c7p >> 21] * f7;
        }
    }
    h[(size_t)dst * HID + lane] = acc;
}

// ---- gcompute: g[gi] = h[src] @ w1[ss] for each flagged col ------------------
// A-values are wave-uniform -> fetched via the SCALAR pipe (readfirstlane'd
// row pointers => s_load), per-lane wk from LDS (conflict-free b32).
// No hs staging: each h row is exactly four 64B-line scalar fetches.
__global__ __launch_bounds__(256) void gcompute_kernel(const int* __restrict__ collist,
                                                       const int* __restrict__ ncols_p,
                                                       const float* __restrict__ h,
                                                       const float* __restrict__ w1,
                                                       float* __restrict__ g) {
    __shared__ float w1s[HID * HID];     // 16 KB
    const int ncols = *ncols_p;
    const int base = blockIdx.x * GC_COLS;
    if (base >= ncols) return;           // uniform early-exit
    const int lane = threadIdx.x & 63;
    const int wid  = __builtin_amdgcn_readfirstlane(threadIdx.x >> 6);

    int lastr = min(base + GC_COLS - 1, ncols - 1);
    int ss0 = __builtin_amdgcn_readfirstlane((int)((unsigned)collist[base] / NN));
    int ssL = __builtin_amdgcn_readfirstlane((int)((unsigned)collist[lastr] / NN));
    bool uni = (ss0 == ssL);

    {   // stage w1[ss0] (4096 floats = 1024 float4, 256 threads x 4)
        const float4* src = (const float4*)(w1 + (size_t)ss0 * HID * HID);
        float4* dst = (float4*)w1s;
#pragma unroll
        for (int i = 0; i < 4; ++i) dst[threadIdx.x + 256 * i] = src[threadIdx.x + 256 * i];
    }
    __syncthreads();

    float acc[16];
#pragma unroll
    for (int i = 0; i < 16; ++i) acc[i] = 0.f;

    if (uni) {
        int srcu[16];                    // wave-uniform h row indices (SGPRs)
#pragma unroll
        for (int ii = 0; ii < 16; ++ii) {
            int r = min(base + wid * 16 + ii, ncols - 1);
            srcu[ii] = __builtin_amdgcn_readfirstlane(collist[r]) - ss0 * NN;
        }
#pragma unroll 1
        for (int kc = 0; kc < 4; ++kc) {
            float wk[16];
#pragma unroll
            for (int k = 0; k < 16; ++k) wk[k] = w1s[(kc * 16 + k) * HID + lane];
#pragma unroll
            for (int ii = 0; ii < 16; ++ii) {
                const float* hp = h + (size_t)srcu[ii] * HID + kc * 16;   // scalar loads
                float a = acc[ii];
                a += hp[0]  * wk[0];  a += hp[1]  * wk[1];
                a += hp[2]  * wk[2];  a += hp[3]  * wk[3];
                a += hp[4]  * wk[4];  a += hp[5]  * wk[5];
                a += hp[6]  * wk[6];  a += hp[7]  * wk[7];
                a += hp[8]  * wk[8];  a += hp[9]  * wk[9];
                a += hp[10] * wk[10]; a += hp[11] * wk[11];
                a += hp[12] * wk[12]; a += hp[13] * wk[13];
                a += hp[14] * wk[14]; a += hp[15] * wk[15];
                acc[ii] = a;
            }
        }
    } else {
        // rare ss-boundary block: per-row ss, w1 from global (L2-hot)
#pragma unroll 1
        for (int ii = 0; ii < 16; ++ii) {
            int r = base + wid * 16 + ii;
            if (r >= ncols) break;
            int cc = __builtin_amdgcn_readfirstlane(collist[r]);
            int ss = (int)((unsigned)cc / NN);
            const float* hp = h + (size_t)(cc - ss * NN) * HID;
            const float* wp = w1 + (size_t)ss * HID * HID;
            float a = 0.f;
            for (int k = 0; k < HID; ++k) a += hp[k] * wp[k * HID + lane];
            acc[ii] = a;
        }
    }

#pragma unroll
    for (int ii = 0; ii < 16; ++ii) {
        int r = base + wid * 16 + ii;
        if (r < ncols) g[(size_t)r * HID + lane] = acc[ii];
    }
}

// ---- layer 2: wave per flagged dst; ILP-8 groups, NO scalar tail -------------
__global__ __launch_bounds__(256) void layer2_kernel(const int* __restrict__ celloff,
                                                     const int* __restrict__ pay,
                                                     const int* __restrict__ coloff,
                                                     const float* __restrict__ g,
                                                     const float* __restrict__ b1,
                                                     const int* __restrict__ flag,
                                                     float* __restrict__ nodes) {
    __shared__ float lut[256];
    lut[threadIdx.x] = threadIdx.x ? 1.0f / (float)threadIdx.x : 0.f;
    __syncthreads();
    int wv = (blockIdx.x * blockDim.x + threadIdx.x) >> 6;
    int lane = threadIdx.x & 63;
    if (wv >= NN) return;
    int dst = __builtin_amdgcn_readfirstlane(wv);
    if (!flag[dst]) return;
    int beg = celloff[dst * R2];
    int end = celloff[(dst + 1) * R2];      // includes self-loop cell (cnt=1)
    float acc = b1[lane];
    for (int base = beg; base < end; base += 64) {
        int idx = base + lane;
        int colv = (idx < end) ? pay[idx] : 0;               // cnt=0 -> v=0
        int gv   = (idx < end) ? coloff[colv & COL_MASK] : 0;
        int m = __builtin_amdgcn_readfirstlane(min(64, end - base));
        for (int e = 0; e < m; e += 8) {                     // full-8, zero-padded
            int g0 = __shfl(gv, e,     64); int c0p = __shfl(colv, e,     64);
            int g1 = __shfl(gv, e + 1, 64); int c1p = __shfl(colv, e + 1, 64);
            int g2 = __shfl(gv, e + 2, 64); int c2p = __shfl(colv, e + 2, 64);
            int g3 = __shfl(gv, e + 3, 64); int c3p = __shfl(colv, e + 3, 64);
            int g4 = __shfl(gv, e + 4, 64); int c4p = __shfl(colv, e + 4, 64);
            int g5 = __shfl(gv, e + 5, 64); int c5p = __shfl(colv, e + 5, 64);
            int g6 = __shfl(gv, e + 6, 64); int c6p = __shfl(colv, e + 6, 64);
            int g7 = __shfl(gv, e + 7, 64); int c7p = __shfl(colv, e + 7, 64);
            float f0 = g[(size_t)g0 * HID + lane];
            float f1 = g[(size_t)g1 * HID + lane];
            float f2 = g[(size_t)g2 * HID + lane];
            float f3 = g[(size_t)g3 * HID + lane];
            float f4 = g[(size_t)g4 * HID + lane];
            float f5 = g[(size_t)g5 * HID + lane];
            float f6 = g[(size_t)g6 * HID + lane];
            float f7 = g[(size_t)g7 * HID + lane];
            acc += lut[(unsigned)c0p >> 21] * f0;
            acc += lut[(unsigned)c1p >> 21] * f1;
            acc += lut[(unsigned)c2p >> 21] * f2;
            acc += lut[(unsigned)c3p >> 21] * f3;
            acc += lut[(unsigned)c4p >> 21] * f4;
            acc += lut[(unsigned)c5p >> 21] * f5;
            acc += lut[(unsigned)c6p >> 21] * f6;
            acc += lut[(unsigned)c7p >> 21] * f7;
        }
    }
    nodes[(size_t)dst * HID + lane] = acc;
}

// ---- scores: wave per batch item (nodes indexed directly) --------------------
__global__ __launch_bounds__(256) void score_kernel(const int* __restrict__ batch,
                                                    const float* __restrict__ nodes,
                                                    const float* __restrict__ rel,
                                                    float* __restrict__ out) {
    int wave = (blockIdx.x * blockDim.x + threadIdx.x) >> 6;
    int lane = threadIdx.x & 63;
    if (wave >= NB) return;
    int si = batch[3 * wave], pi = batch[3 * wave + 1], oi = batch[3 * wave + 2];
    float a = nodes[(size_t)si * HID + lane];
    float b = nodes[(size_t)oi * HID + lane];
    float v = a * rel[pi * HID + lane] * b;
#pragma unroll
    for (int off = 32; off; off >>= 1) v += __shfl_down(v, off, 64);
    if (lane == 0) out[wave] = v;
}

extern "C" void kernel_launch(void* const* d_in, const int* in_sizes, int n_in,
                              void* d_out, int out_size, void* d_ws, size_t ws_size,
                              hipStream_t stream) {
    const int*   batch   = (const int*)d_in[0];
    const int*   triples = (const int*)d_in[1];
    const float* w0      = (const float*)d_in[2];
    const float* b0      = (const float*)d_in[3];
    const float* w1      = (const float*)d_in[4];
    const float* b1      = (const float*)d_in[5];
    const float* rel     = (const float*)d_in[6];
    float* out = (float*)d_out;

    // ---- workspace layout: [zeroed: celloff | flag | coloff] | rest ----------
    int* celloff  = (int*)d_ws;                         // M+1
    int* flag     = celloff + (M_CELLS + 1);            // NN
    int* coloff   = flag + NN;                          // M+1 (colflag -> offsets)
    unsigned char* cnt8 = (unsigned char*)(coloff + (M_CELLS + 1));  // M bytes
    int* rank     = (int*)(cnt8 + ((M_CELLS + 15) & ~15));           // 2NE
    int* pay      = rank + 2 * NE;                      // 2NE + NN
    int* sums     = pay + (2 * NE + NN);                // SCAN_B (shared by both scans)
    int* collist  = sums + SCAN_B;                      // <= M
    float* h      = (float*)(collist + M_CELLS);        // NN*HID
    float* nodes  = h + (size_t)NN * HID;               // NN*HID
    float* g      = nodes + (size_t)NN * HID;           // <= M*HID (~450k rows used)

    size_t zero_bytes = ((size_t)2 * (M_CELLS + 1) + NN) * 4;   // ~8.6 MB
    hipMemsetAsync(d_ws, 0, zero_bytes, stream);

    const int htot = NE / 4 + NN + 2 * NB;
    hist_kernel<<<(htot + 255) / 256, 256, 0, stream>>>(triples, batch, celloff, rank, flag);

    const int nb = (M_CELLS + 2 * SCAN_B - 1) / (2 * SCAN_B);   // 513
    {   // exclusive scan of celloff counts (+cnt8 emit), total -> celloff[M]
        scan1_kernel<<<nb, SCAN_B, 0, stream>>>(celloff, sums, M_CELLS, cnt8);
        scan2_kernel<<<1, SCAN_B, 0, stream>>>(sums, nb, celloff + M_CELLS);
        scan3_kernel<<<nb, SCAN_B, 0, stream>>>(celloff, sums, M_CELLS);
    }

    const int stot = NE / 4 + NN;
    scatter_kernel<<<(stot + 255) / 256, 256, 0, stream>>>(triples, celloff, rank, flag,
                                                           cnt8, pay, coloff);

    {   // exclusive scan of colflag -> g-row offsets, total (ncols) -> coloff[M]
        scan1_kernel<<<nb, SCAN_B, 0, stream>>>(coloff, sums, M_CELLS, nullptr);
        scan2_kernel<<<1, SCAN_B, 0, stream>>>(sums, nb, coloff + M_CELLS);
        scan3_kernel<<<nb, SCAN_B, 0, stream>>>(coloff, sums, M_CELLS);
    }

    layer1_kernel<<<(NN * 64 + 255) / 256, 256, 0, stream>>>(celloff, pay, w0, b0,
                                                             coloff, collist, h);

    gcompute_kernel<<<(M_CELLS + GC_COLS - 1) / GC_COLS, 256, 0, stream>>>(collist,
                                                             coloff + M_CELLS, h, w1, g);

    layer2_kernel<<<(NN * 64 + 255) / 256, 256, 0, stream>>>(celloff, pay, coloff,
                                                             g, b1, flag, nodes);

    score_kernel<<<(NB * 64 + 255) / 256, 256, 0, stream>>>(batch, nodes, rel, out);
}